// Round 1
// baseline (254.450 us; speedup 1.0000x reference)
//
#include <hip/hip_runtime.h>
#include <math.h>

typedef unsigned short u16;
using bf16x8 = __attribute__((ext_vector_type(8))) short;
using f32x4  = __attribute__((ext_vector_type(4))) float;

#define NS      128
#define NBLOCKS 4096    // 1 ray per block, 512 threads (8 waves)
#define KS1     15      // 30 channels * 16 slots = 480 K
#define NSLICE  19      // 15 (W1) + 4 (W2) unified W slices of 4096 u16

// LDS pool (u16 units): X double-buffer (2 x 4096), overlaid by h (16384 u16
// = 32 KB, A-frag order with XOR swizzle). No W staging: B-frags are read
// straight from L2-resident ws (already in B-frag order) into registers.
#define OX0   0
#define OX1   4096
#define POOLSZ 16384

__device__ __forceinline__ u16 f2bf(float f) {           // host-prep path only
    unsigned int i = __float_as_uint(f);
    return (u16)((i + 0x7FFFu + ((i >> 16) & 1u)) >> 16);  // RNE
}

// pack two floats to bf16 pair [hi:lo] in one dword (single VALU op, RNE)
__device__ __forceinline__ unsigned pk(float hi, float lo) {
    unsigned r;
    asm("v_cvt_pk_bf16_f32 %0, %1, %2" : "=v"(r) : "v"(lo), "v"(hi));
    return r;
}
__device__ __forceinline__ u16 f2bf1(float f) {
    return (u16)((__float_as_uint(f) + 0x8000u) >> 16);
}

// Swizzled A-frag-order offset for the h [128x128] region: XOR the k-octet
// bits into the chunk index so the epilogue's column-wise u16 writes spread
// across ~2x more banks. Readers (A-frag ds_read_b128 at chunk = T*64+lane)
// apply chunk^quad, which keeps the 64 lanes on 64 distinct 16B chunks.
__device__ __forceinline__ int afoff_h(int m, int k) {
    int chunk = ((k >> 5) * 8 + (m >> 4)) * 64 + ((k >> 3) & 3) * 16 + (m & 15);
    chunk ^= (k >> 3) & 3;
    return chunk * 8 + (k & 7);
}

// channel/slot -> original mlp_in k index (reference ordering)
__device__ __forceinline__ int orig_k(int ch, int slot) {
    if (ch < 27) {
        if (slot == 0) return ch;
        if (slot <= 6) return 30 + ch * 6 + (slot - 1);     // sin(app)
        return 192 + ch * 6 + (slot - 7);                    // cos(app)
    } else {
        int c = ch - 27;
        if (slot == 0) return 27 + c;
        if (slot <= 6) return 354 + c * 6 + (slot - 1);      // sin(view)
        return 372 + c * 6 + (slot - 7);                     // cos(view)
    }
}

// build one channel-half of a frag-order X slice: thread (m_b, cl_b) owns
// chunks 2cl_b, 2cl_b+1 of group g=m_b>>4; slots [v, sin f0..5, cos f0..5, 0x3]
__device__ __forceinline__ void build_x(u16* Xb, int m_b, int cl_b, float v) {
    float rev = v * 0.15915494309189535f;
    rev -= floorf(rev);
    float s0 = __builtin_amdgcn_sinf(rev);
    float c0 = __builtin_amdgcn_cosf(rev);
    float s1 = 2.f * s0 * c0, c1 = c0 * c0 - s0 * s0;
    float s2 = 2.f * s1 * c1, c2 = c1 * c1 - s1 * s1;
    float s3 = 2.f * s2 * c2, c3 = c2 * c2 - s2 * s2;
    float s4 = 2.f * s3 * c3, c4 = c3 * c3 - s3 * s3;
    float s5 = 2.f * s4 * c4, c5 = c4 * c4 - s4 * s4;
    uint4 lo, hi;
    lo.x = pk(s0, v);  lo.y = pk(s2, s1);  lo.z = pk(s4, s3);  lo.w = pk(c0, s5);
    hi.x = pk(c2, c1); hi.y = pk(c4, c3);  hi.z = pk(0.f, c5); hi.w = 0u;
    int base = (m_b >> 4) * 512 + ((2 * cl_b) * 16 + (m_b & 15)) * 8;
    *(uint4*)(Xb + base)       = lo;   // chunk 2*cl_b
    *(uint4*)(Xb + base + 128) = hi;   // chunk 2*cl_b+1 (+16*8 u16)
}

// W1 -> 15 slices, W2 -> 4 slices, W3 -> 4 mini B-frag slices (N padded 16)
__global__ __launch_bounds__(256) void prep_kernel(
    const float* __restrict__ W1, const float* __restrict__ W2,
    const float* __restrict__ W3, u16* __restrict__ ws)
{
    int idx = blockIdx.x * 256 + threadIdx.x;
    if (idx < 61440) {                               // W1r: [ks15][nt8][lane64][j8]
        int j = idx & 7, lane = (idx >> 3) & 63, nt = (idx >> 9) & 7, ks = idx >> 12;
        int q = lane >> 4, l15 = lane & 15;
        int klocal = q * 8 + j;                      // 0..31
        int ch = ks * 2 + (klocal >> 4);
        int slot = klocal & 15;
        int n = nt * 16 + l15;
        ws[idx] = (slot < 13) ? f2bf(W1[orig_k(ch, slot) * 128 + n]) : (u16)0;
    } else if (idx < 77824) {                        // W2r: [ks4][nt8][lane64][j8]
        int i2 = idx - 61440;
        int j = i2 & 7, lane = (i2 >> 3) & 63, nt = (i2 >> 9) & 7, ks = i2 >> 12;
        int k = ks * 32 + (lane >> 4) * 8 + j;
        int n = nt * 16 + (lane & 15);
        ws[idx] = f2bf(W2[k * 128 + n]);
    } else if (idx < 79872) {                        // W3r: [ks4][lane64][j8], N pad 16
        int i3 = idx - 77824;
        int j = i3 & 7, lane = (i3 >> 3) & 63, ks = i3 >> 9;
        int k = ks * 32 + (lane >> 4) * 8 + j;
        int n = lane & 15;
        ws[idx] = (n < 3) ? f2bf(W3[k * 3 + n]) : (u16)0;
    }
}

// 8 waves: wave (wm = wave>>2, wn = wave&3) owns a 64x32 output tile
// -> acc is 4x2 f32x4 = 32 regs -> total GPRs < 128 -> 4 waves/SIMD.
__global__ __launch_bounds__(512, 4) void render_kernel(
    const float* __restrict__ sigma_g, const float* __restrict__ app_g,
    const float* __restrict__ view_g,  const float* __restrict__ dists_g,
    const float* __restrict__ b1_g,    const float* __restrict__ b2_g,
    const float* __restrict__ b3_g,    const u16* __restrict__ ws,
    float* __restrict__ out_g)
{
    __shared__ __align__(16) u16 pool[POOLSZ];
    __shared__ __align__(16) float part[NS * 3];
    __shared__ float scanS;          // wave0 scan total broadcast
    __shared__ float sum2[6];        // per-wave final partials

    const int tid  = threadIdx.x;
    const int lane = tid & 63;
    const int wave = tid >> 6;       // 0..7
    const int l15  = lane & 15;
    const int quad = lane >> 4;
    const int wm   = wave >> 2;      // row half (64 rows)
    const int wn   = wave & 3;       // col quarter (32 cols)

    const u16* w3r = ws + 77824;

    // per-kernel constants in registers
    float b1r[2], b2r[2];
    #pragma unroll
    for (int nt = 0; nt < 2; ++nt) {
        int col = wn * 32 + nt * 16 + l15;
        b1r[nt] = b1_g[col];
        b2r[nt] = b2_g[col];
    }
    const float b3v = (l15 < 3) ? b3_g[l15] : 0.f;
    bf16x8 w3fr[4];
    #pragma unroll
    for (int ks = 0; ks < 4; ++ks)
        w3fr[ks] = *(const bf16x8*)(w3r + (ks * 64 + lane) * 8);

    const int r  = blockIdx.x;
    const int rb = r * NS;
    const int  m_b     = (tid >> 1) & 127;   // X-build row (builders only)
    const int  cl_b    = tid & 1;            // X-build channel-local
    const bool builder = (tid < 256);        // waves 0..3 build X slices
    const float* ap = app_g  + (rb + m_b) * 27;
    const float* vp = view_g + (rb + m_b) * 3;

    // ---- rolling input prefetch: only 2 values resident ----
    float pv_cur = 0.f, pv_nxt = 0.f;
    if (builder) {
        pv_cur = ap[cl_b];                   // ch = cl_b (slice 0)
        pv_nxt = ap[2 + cl_b];               // ch = 2+cl_b (slice 1)
    }

    // ---- alpha + shuffle transmittance scan (waves 0,1) ----
    float alpha = 0.f, prod = 1.f, wr = 0.f;
    if (tid < NS) {
        float x  = sigma_g[rb + tid] - 10.f;
        float sp = (x > 20.f) ? x : log1pf(expf(x));
        alpha = 1.f - expf(-sp * dists_g[rb + tid] * 25.f);
        if (tid == NS - 1) alpha = 1.f;
        float tb = 1.f - alpha + 1e-10f;
        prod = tb;
        #pragma unroll
        for (int d = 1; d < 64; d <<= 1) {
            float v = __shfl_up(prod, d);
            if (lane >= d) prod *= v;
        }
        if (tid == 63) scanS = prod;
    }

    // ---- build X slice 0 (channels 0,1) ----
    if (builder) {
        build_x(pool + OX0, m_b, cl_b, pv_cur);
        pv_cur = pv_nxt;
    }
    __syncthreads();

    // finish weights: wr = alpha * T_exclusive
    if (tid < NS) {
        float prev = __shfl_up(prod, 1);
        float base = (lane == 0) ? 1.f : prev;
        float scale = (wave == 1) ? scanS : 1.f;
        wr = alpha * base * scale;
    }

    // ---- unified 19-slice K-loop: GEMM1 (0..14) + GEMM2 (15..18) ----
    const f32x4 vzero = {0.f, 0.f, 0.f, 0.f};
    f32x4 acc[4][2];
    #pragma unroll
    for (int mt = 0; mt < 4; ++mt)
        #pragma unroll
        for (int nt = 0; nt < 2; ++nt) acc[mt][nt] = vzero;

    // B-frags straight from global (L2-hot, frag-order): double-buffered regs
    const u16* wp0 = ws + (wn * 128 + lane) * 8;
    bf16x8 bA[2], bB[2];
    bA[0] = *(const bf16x8*)(wp0);
    bA[1] = *(const bf16x8*)(wp0 + 512);

    auto body = [&](int i, bf16x8* bc, bf16x8* bn) {
        if (i + 1 < NSLICE) {                 // prefetch next-slice B-frags
            const u16* wp = wp0 + (i + 1) * 4096;
            bn[0] = *(const bf16x8*)(wp);
            bn[1] = *(const bf16x8*)(wp + 512);
        }
        if (builder && i + 2 < KS1) {         // issue input for slice i+2
            int ch = 2 * (i + 2) + cl_b;
            pv_nxt = (ch < 27) ? ap[ch] : vp[ch - 27];
        }
        bf16x8 a[4];
        if (i < KS1) {                        // A from X double-buffer (linear)
            const u16* Asrc = pool + (((i & 1) == 0) ? OX0 : OX1);
            #pragma unroll
            for (int mt = 0; mt < 4; ++mt)
                a[mt] = *(const bf16x8*)(Asrc + ((wm * 4 + mt) * 64 + lane) * 8);
        } else {                              // A from h (XOR-swizzled chunks)
            #pragma unroll
            for (int mt = 0; mt < 4; ++mt) {
                int c = (i - KS1) * 512 + (wm * 4 + mt) * 64 + lane;
                a[mt] = *(const bf16x8*)(pool + (c ^ quad) * 8);
            }
        }
        #pragma unroll
        for (int nt = 0; nt < 2; ++nt)
            #pragma unroll
            for (int mt = 0; mt < 4; ++mt)
                acc[mt][nt] = __builtin_amdgcn_mfma_f32_16x16x32_bf16(
                    a[mt], bc[nt], acc[mt][nt], 0, 0, 0);
        if (builder && i < KS1 - 1) {         // build X slice i+1
            u16* Xb = pool + ((((i + 1) & 1) == 0) ? OX0 : OX1);
            build_x(Xb, m_b, cl_b, pv_cur);
            pv_cur = pv_nxt;
        }
        if (i == KS1 - 1) {
            // all waves must finish slice-14 A-reads before h overwrites X
            __syncthreads();
            // epilogue 1: h1 = relu(acc + b1) -> h (bf16, swizzled frag order)
            #pragma unroll
            for (int mt = 0; mt < 4; ++mt)
                #pragma unroll
                for (int nt = 0; nt < 2; ++nt) {
                    int col = wn * 32 + nt * 16 + l15;
                    #pragma unroll
                    for (int rr = 0; rr < 4; ++rr) {
                        int row = wm * 64 + mt * 16 + quad * 4 + rr;
                        pool[afoff_h(row, col)] =
                            f2bf1(fmaxf(acc[mt][nt][rr] + b1r[nt], 0.f));
                    }
                    acc[mt][nt] = vzero;      // reset for GEMM2
                }
        }
        __syncthreads();
    };

    #pragma unroll 1
    for (int t = 0; t < 9; ++t) {
        body(2 * t,     bA, bB);
        body(2 * t + 1, bB, bA);
    }
    body(18, bA, bB);

    // ---- epilogue 2: h2 = relu(acc + b2) -> overlays h1 ----
    #pragma unroll
    for (int mt = 0; mt < 4; ++mt)
        #pragma unroll
        for (int nt = 0; nt < 2; ++nt) {
            int col = wn * 32 + nt * 16 + l15;
            #pragma unroll
            for (int rr = 0; rr < 4; ++rr) {
                int row = wm * 64 + mt * 16 + quad * 4 + rr;
                pool[afoff_h(row, col)] =
                    f2bf1(fmaxf(acc[mt][nt][rr] + b2r[nt], 0.f));
            }
        }
    __syncthreads();

    // ---- layer 3 via MFMA: rgb = sigmoid(h2 @ W3 + b3); wave = row-tile ----
    f32x4 acc3 = vzero;
    #pragma unroll
    for (int ks = 0; ks < 4; ++ks) {
        int c = (ks * 8 + wave) * 64 + lane;
        bf16x8 a3 = *(const bf16x8*)(pool + (c ^ quad) * 8);
        acc3 = __builtin_amdgcn_mfma_f32_16x16x32_bf16(a3, w3fr[ks], acc3, 0, 0, 0);
    }
    if (l15 < 3) {
        #pragma unroll
        for (int rr = 0; rr < 4; ++rr) {
            int row = wave * 16 + quad * 4 + rr;
            float v = acc3[rr] + b3v;
            part[row * 3 + l15] = 1.f / (1.f + expf(-v));
        }
    }
    __syncthreads();

    // ---- weighted sum over samples ----
    if (tid < NS) {
        float v0 = wr * part[tid * 3 + 0];
        float v1 = wr * part[tid * 3 + 1];
        float v2 = wr * part[tid * 3 + 2];
        #pragma unroll
        for (int d = 1; d < 64; d <<= 1) {
            v0 += __shfl_xor(v0, d);
            v1 += __shfl_xor(v1, d);
            v2 += __shfl_xor(v2, d);
        }
        if (lane == 0) {
            sum2[wave * 3 + 0] = v0;
            sum2[wave * 3 + 1] = v1;
            sum2[wave * 3 + 2] = v2;
        }
    }
    __syncthreads();
    if (tid == 0) {
        out_g[r * 3 + 0] = sum2[0] + sum2[3];
        out_g[r * 3 + 1] = sum2[1] + sum2[4];
        out_g[r * 3 + 2] = sum2[2] + sum2[5];
    }
}

extern "C" void kernel_launch(void* const* d_in, const int* in_sizes, int n_in,
                              void* d_out, int out_size, void* d_ws, size_t ws_size,
                              hipStream_t stream) {
    (void)in_sizes; (void)n_in; (void)out_size; (void)ws_size;
    const float* sigma = (const float*)d_in[0];
    const float* app   = (const float*)d_in[1];
    const float* view  = (const float*)d_in[2];
    const float* dists = (const float*)d_in[3];
    const float* W1    = (const float*)d_in[4];
    const float* b1    = (const float*)d_in[5];
    const float* W2    = (const float*)d_in[6];
    const float* b2    = (const float*)d_in[7];
    const float* W3    = (const float*)d_in[8];
    const float* b3    = (const float*)d_in[9];
    float* out = (float*)d_out;

    u16* ws = (u16*)d_ws;   // 61440 (W1r) + 16384 (W2r) + 2048 (W3r) u16 = 159744 B

    prep_kernel<<<312, 256, 0, stream>>>(W1, W2, W3, ws);
    render_kernel<<<NBLOCKS, 512, 0, stream>>>(sigma, app, view, dists,
                                               b1, b2, b3, ws, out);
}

// Round 2
// 216.389 us; speedup vs baseline: 1.1759x; 1.1759x over previous
//
#include <hip/hip_runtime.h>
#include <math.h>

typedef unsigned short u16;
using bf16x8 = __attribute__((ext_vector_type(8))) short;
using f32x4  = __attribute__((ext_vector_type(4))) float;

#define NS      128
#define NBLOCKS 4096    // 1 ray per block, 512 threads (8 waves)
#define KS1     15      // 30 channels * 16 slots = 480 K
#define NSLICE  19      // 15 (W1) + 4 (W2) unified W slices of 4096 u16

// LDS pool (u16 units): X double-buffer (2 x 4096), overlaid by h (16384 u16
// = 32 KB, A-frag order with XOR swizzle). No W staging: B-frags are read
// straight from L2-resident ws (already in B-frag order) into registers.
#define OX0   0
#define OX1   4096
#define POOLSZ 16384

__device__ __forceinline__ u16 f2bf(float f) {           // host-prep path only
    unsigned int i = __float_as_uint(f);
    return (u16)((i + 0x7FFFu + ((i >> 16) & 1u)) >> 16);  // RNE
}

// pack two floats to bf16 pair [hi:lo] in one dword (single VALU op, RNE)
__device__ __forceinline__ unsigned pk(float hi, float lo) {
    unsigned r;
    asm("v_cvt_pk_bf16_f32 %0, %1, %2" : "=v"(r) : "v"(lo), "v"(hi));
    return r;
}
__device__ __forceinline__ u16 f2bf1(float f) {
    return (u16)((__float_as_uint(f) + 0x8000u) >> 16);
}

// Swizzled A-frag-order offset for the h [128x128] region: XOR (k>>3)&3 into
// the chunk index (same bijection applied by readers via chunk^quad), which
// spreads the epilogue's column-wise u16 writes across more banks while
// keeping A-frag ds_read_b128 lane-bijective.
__device__ __forceinline__ int afoff_h(int m, int k) {
    int chunk = ((k >> 5) * 8 + (m >> 4)) * 64 + ((k >> 3) & 3) * 16 + (m & 15);
    chunk ^= (k >> 3) & 3;
    return chunk * 8 + (k & 7);
}

// channel/slot -> original mlp_in k index (reference ordering)
__device__ __forceinline__ int orig_k(int ch, int slot) {
    if (ch < 27) {
        if (slot == 0) return ch;
        if (slot <= 6) return 30 + ch * 6 + (slot - 1);     // sin(app)
        return 192 + ch * 6 + (slot - 7);                    // cos(app)
    } else {
        int c = ch - 27;
        if (slot == 0) return 27 + c;
        if (slot <= 6) return 354 + c * 6 + (slot - 1);      // sin(view)
        return 372 + c * 6 + (slot - 7);                     // cos(view)
    }
}

// build one channel-half of a frag-order X slice: thread (m_b, cl_b) owns
// chunks 2cl_b, 2cl_b+1 of group g=m_b>>4; slots [v, sin f0..5, cos f0..5, 0x3]
__device__ __forceinline__ void build_x(u16* Xb, int m_b, int cl_b, float v) {
    float rev = v * 0.15915494309189535f;
    rev -= floorf(rev);
    float s0 = __builtin_amdgcn_sinf(rev);
    float c0 = __builtin_amdgcn_cosf(rev);
    float s1 = 2.f * s0 * c0, c1 = c0 * c0 - s0 * s0;
    float s2 = 2.f * s1 * c1, c2 = c1 * c1 - s1 * s1;
    float s3 = 2.f * s2 * c2, c3 = c2 * c2 - s2 * s2;
    float s4 = 2.f * s3 * c3, c4 = c3 * c3 - s3 * s3;
    float s5 = 2.f * s4 * c4, c5 = c4 * c4 - s4 * s4;
    uint4 lo, hi;
    lo.x = pk(s0, v);  lo.y = pk(s2, s1);  lo.z = pk(s4, s3);  lo.w = pk(c0, s5);
    hi.x = pk(c2, c1); hi.y = pk(c4, c3);  hi.z = pk(0.f, c5); hi.w = 0u;
    int base = (m_b >> 4) * 512 + ((2 * cl_b) * 16 + (m_b & 15)) * 8;
    *(uint4*)(Xb + base)       = lo;   // chunk 2*cl_b
    *(uint4*)(Xb + base + 128) = hi;   // chunk 2*cl_b+1 (+16*8 u16)
}

// W1 -> 15 slices, W2 -> 4 slices, W3 -> 4 mini B-frag slices (N padded 16)
__global__ __launch_bounds__(256) void prep_kernel(
    const float* __restrict__ W1, const float* __restrict__ W2,
    const float* __restrict__ W3, u16* __restrict__ ws)
{
    int idx = blockIdx.x * 256 + threadIdx.x;
    if (idx < 61440) {                               // W1r: [ks15][nt8][lane64][j8]
        int j = idx & 7, lane = (idx >> 3) & 63, nt = (idx >> 9) & 7, ks = idx >> 12;
        int q = lane >> 4, l15 = lane & 15;
        int klocal = q * 8 + j;                      // 0..31
        int ch = ks * 2 + (klocal >> 4);
        int slot = klocal & 15;
        int n = nt * 16 + l15;
        ws[idx] = (slot < 13) ? f2bf(W1[orig_k(ch, slot) * 128 + n]) : (u16)0;
    } else if (idx < 77824) {                        // W2r: [ks4][nt8][lane64][j8]
        int i2 = idx - 61440;
        int j = i2 & 7, lane = (i2 >> 3) & 63, nt = (i2 >> 9) & 7, ks = i2 >> 12;
        int k = ks * 32 + (lane >> 4) * 8 + j;
        int n = nt * 16 + (lane & 15);
        ws[idx] = f2bf(W2[k * 128 + n]);
    } else if (idx < 79872) {                        // W3r: [ks4][lane64][j8], N pad 16
        int i3 = idx - 77824;
        int j = i3 & 7, lane = (i3 >> 3) & 63, ks = i3 >> 9;
        int k = ks * 32 + (lane >> 4) * 8 + j;
        int n = lane & 15;
        ws[idx] = (n < 3) ? f2bf(W3[k * 3 + n]) : (u16)0;
    }
}

// One K-slice of the unified GEMM loop. Macro (not lambda/function) so the
// B double-buffer lives in NAMED registers -- nothing indexable can be
// demoted to scratch. BC0/BC1 = current slice B-frags, BN0/BN1 = prefetch dst.
#define BODY(i, BC0, BC1, BN0, BN1)                                           \
  {                                                                           \
    if ((i) + 1 < NSLICE) {                 /* prefetch next-slice B-frags */ \
        const u16* wp = wp0 + ((i) + 1) * 4096;                               \
        BN0 = *(const bf16x8*)(wp);                                           \
        BN1 = *(const bf16x8*)(wp + 512);                                     \
    }                                                                         \
    if (builder && (i) + 2 < KS1) {         /* issue input for slice i+2 */   \
        int ch = 2 * ((i) + 2) + cl_b;                                        \
        pv_nxt = (ch < 27) ? ap[ch] : vp[ch - 27];                            \
    }                                                                         \
    bf16x8 a[4];                                                              \
    if ((i) < KS1) {                        /* A from X double-buffer */      \
        const u16* ab = pool + ((((i) & 1) == 0) ? OX0 : OX1)                 \
                        + (wm * 256 + lane) * 8;                              \
        a[0] = *(const bf16x8*)(ab);                                          \
        a[1] = *(const bf16x8*)(ab + 512);                                    \
        a[2] = *(const bf16x8*)(ab + 1024);                                   \
        a[3] = *(const bf16x8*)(ab + 1536);                                   \
    } else {                                /* A from h (swizzled chunks) */  \
        int cb = (((i) - KS1) * 512 + wm * 256 + lane) ^ quad;                \
        a[0] = *(const bf16x8*)(pool + cb * 8);                               \
        a[1] = *(const bf16x8*)(pool + (cb + 64) * 8);                        \
        a[2] = *(const bf16x8*)(pool + (cb + 128) * 8);                       \
        a[3] = *(const bf16x8*)(pool + (cb + 192) * 8);                       \
    }                                                                         \
    _Pragma("unroll")                                                         \
    for (int mt = 0; mt < 4; ++mt) {                                          \
        acc[mt][0] = __builtin_amdgcn_mfma_f32_16x16x32_bf16(                 \
            a[mt], BC0, acc[mt][0], 0, 0, 0);                                 \
        acc[mt][1] = __builtin_amdgcn_mfma_f32_16x16x32_bf16(                 \
            a[mt], BC1, acc[mt][1], 0, 0, 0);                                 \
    }                                                                         \
    if (builder && (i) < KS1 - 1) {         /* build X slice i+1 */           \
        u16* Xb = pool + (((((i) + 1) & 1) == 0) ? OX0 : OX1);                \
        build_x(Xb, m_b, cl_b, pv_cur);                                       \
        pv_cur = pv_nxt;                                                      \
    }                                                                         \
    if ((i) == KS1 - 1) {                                                     \
        /* all waves must finish slice-14 A-reads before h overwrites X */    \
        __syncthreads();                                                      \
        _Pragma("unroll")                                                     \
        for (int mt = 0; mt < 4; ++mt)                                        \
            _Pragma("unroll")                                                 \
            for (int nt = 0; nt < 2; ++nt) {                                  \
                int col = wn * 32 + nt * 16 + l15;                            \
                _Pragma("unroll")                                             \
                for (int rr = 0; rr < 4; ++rr) {                              \
                    int row = wm * 64 + mt * 16 + quad * 4 + rr;              \
                    pool[afoff_h(row, col)] =                                 \
                        f2bf1(fmaxf(acc[mt][nt][rr] + ((nt == 0) ? b1r0       \
                                                                 : b1r1),     \
                                    0.f));                                    \
                }                                                             \
                acc[mt][nt] = vzero;        /* reset for GEMM2 */             \
            }                                                                 \
    }                                                                         \
    __syncthreads();                                                          \
  }

// 8 waves: wave (wm = wave>>2, wn = wave&3) owns a 64x32 output tile
// -> acc is 4x2 f32x4 = 32 regs; w3/b2/b3 loads deferred past the K-loop
// -> in-loop total < 128 regs -> 4 waves/SIMD with no spill.
__global__ __launch_bounds__(512, 4) void render_kernel(
    const float* __restrict__ sigma_g, const float* __restrict__ app_g,
    const float* __restrict__ view_g,  const float* __restrict__ dists_g,
    const float* __restrict__ b1_g,    const float* __restrict__ b2_g,
    const float* __restrict__ b3_g,    const u16* __restrict__ ws,
    float* __restrict__ out_g)
{
    __shared__ __align__(16) u16 pool[POOLSZ];
    __shared__ __align__(16) float part[NS * 3];
    __shared__ float scanS;          // wave0 scan total broadcast
    __shared__ float sum2[6];        // per-wave final partials

    const int tid  = threadIdx.x;
    const int lane = tid & 63;
    const int wave = tid >> 6;       // 0..7
    const int l15  = lane & 15;
    const int quad = lane >> 4;
    const int wm   = wave >> 2;      // row half (64 rows)
    const int wn   = wave & 3;       // col quarter (32 cols)

    // b1 needed inside the loop (slice-14 epilogue): keep just 2 regs
    const float b1r0 = b1_g[wn * 32 + l15];
    const float b1r1 = b1_g[wn * 32 + 16 + l15];

    const int r  = blockIdx.x;
    const int rb = r * NS;
    const int  m_b     = (tid >> 1) & 127;   // X-build row (builders only)
    const int  cl_b    = tid & 1;            // X-build channel-local
    const bool builder = (tid < 256);        // waves 0..3 build X slices
    const float* ap = app_g  + (rb + m_b) * 27;
    const float* vp = view_g + (rb + m_b) * 3;

    // ---- rolling input prefetch: only 2 values resident ----
    float pv_cur = 0.f, pv_nxt = 0.f;
    if (builder) {
        pv_cur = ap[cl_b];                   // ch = cl_b (slice 0)
        pv_nxt = ap[2 + cl_b];               // ch = 2+cl_b (slice 1)
    }

    // ---- alpha + shuffle transmittance scan (waves 0,1) ----
    float alpha = 0.f, prod = 1.f, wr = 0.f;
    if (tid < NS) {
        float x  = sigma_g[rb + tid] - 10.f;
        float sp = (x > 20.f) ? x : log1pf(expf(x));
        alpha = 1.f - expf(-sp * dists_g[rb + tid] * 25.f);
        if (tid == NS - 1) alpha = 1.f;
        float tb = 1.f - alpha + 1e-10f;
        prod = tb;
        #pragma unroll
        for (int d = 1; d < 64; d <<= 1) {
            float v = __shfl_up(prod, d);
            if (lane >= d) prod *= v;
        }
        if (tid == 63) scanS = prod;
    }

    // ---- build X slice 0 (channels 0,1) ----
    if (builder) {
        build_x(pool + OX0, m_b, cl_b, pv_cur);
        pv_cur = pv_nxt;
    }
    __syncthreads();

    // finish weights: wr = alpha * T_exclusive
    if (tid < NS) {
        float prev = __shfl_up(prod, 1);
        float base = (lane == 0) ? 1.f : prev;
        float scale = (wave == 1) ? scanS : 1.f;
        wr = alpha * base * scale;
    }

    // ---- unified 19-slice K-loop: GEMM1 (0..14) + GEMM2 (15..18) ----
    const f32x4 vzero = {0.f, 0.f, 0.f, 0.f};
    f32x4 acc[4][2];
    #pragma unroll
    for (int mt = 0; mt < 4; ++mt)
        #pragma unroll
        for (int nt = 0; nt < 2; ++nt) acc[mt][nt] = vzero;

    // B-frags straight from global (L2-hot, frag-order): named reg dbuf
    const u16* wp0 = ws + (wn * 128 + lane) * 8;
    bf16x8 bA0, bA1, bB0, bB1;
    bA0 = *(const bf16x8*)(wp0);
    bA1 = *(const bf16x8*)(wp0 + 512);

    #pragma unroll 1
    for (int t = 0; t < 9; ++t) {
        BODY(2 * t,     bA0, bA1, bB0, bB1);
        BODY(2 * t + 1, bB0, bB1, bA0, bA1);
    }
    BODY(18, bA0, bA1, bB0, bB1);

    // ---- epilogue 2: h2 = relu(acc + b2) -> overlays h1 (b2 loaded NOW) ----
    const float b2r0 = b2_g[wn * 32 + l15];
    const float b2r1 = b2_g[wn * 32 + 16 + l15];
    #pragma unroll
    for (int mt = 0; mt < 4; ++mt)
        #pragma unroll
        for (int nt = 0; nt < 2; ++nt) {
            int col = wn * 32 + nt * 16 + l15;
            #pragma unroll
            for (int rr = 0; rr < 4; ++rr) {
                int row = wm * 64 + mt * 16 + quad * 4 + rr;
                pool[afoff_h(row, col)] =
                    f2bf1(fmaxf(acc[mt][nt][rr] + ((nt == 0) ? b2r0 : b2r1), 0.f));
            }
        }
    __syncthreads();

    // ---- layer 3 via MFMA: rgb = sigmoid(h2 @ W3 + b3); wave = row-tile ----
    const u16* w3r = ws + 77824;
    const float b3v = (l15 < 3) ? b3_g[l15] : 0.f;
    f32x4 acc3 = vzero;
    #pragma unroll
    for (int ks = 0; ks < 4; ++ks) {
        bf16x8 w3f = *(const bf16x8*)(w3r + (ks * 64 + lane) * 8);
        int c = ((ks * 8 + wave) * 64 + lane) ^ quad;
        bf16x8 a3 = *(const bf16x8*)(pool + c * 8);
        acc3 = __builtin_amdgcn_mfma_f32_16x16x32_bf16(a3, w3f, acc3, 0, 0, 0);
    }
    if (l15 < 3) {
        #pragma unroll
        for (int rr = 0; rr < 4; ++rr) {
            int row = wave * 16 + quad * 4 + rr;
            float v = acc3[rr] + b3v;
            part[row * 3 + l15] = 1.f / (1.f + expf(-v));
        }
    }
    __syncthreads();

    // ---- weighted sum over samples ----
    if (tid < NS) {
        float v0 = wr * part[tid * 3 + 0];
        float v1 = wr * part[tid * 3 + 1];
        float v2 = wr * part[tid * 3 + 2];
        #pragma unroll
        for (int d = 1; d < 64; d <<= 1) {
            v0 += __shfl_xor(v0, d);
            v1 += __shfl_xor(v1, d);
            v2 += __shfl_xor(v2, d);
        }
        if (lane == 0) {
            sum2[wave * 3 + 0] = v0;
            sum2[wave * 3 + 1] = v1;
            sum2[wave * 3 + 2] = v2;
        }
    }
    __syncthreads();
    if (tid == 0) {
        out_g[r * 3 + 0] = sum2[0] + sum2[3];
        out_g[r * 3 + 1] = sum2[1] + sum2[4];
        out_g[r * 3 + 2] = sum2[2] + sum2[5];
    }
}

extern "C" void kernel_launch(void* const* d_in, const int* in_sizes, int n_in,
                              void* d_out, int out_size, void* d_ws, size_t ws_size,
                              hipStream_t stream) {
    (void)in_sizes; (void)n_in; (void)out_size; (void)ws_size;
    const float* sigma = (const float*)d_in[0];
    const float* app   = (const float*)d_in[1];
    const float* view  = (const float*)d_in[2];
    const float* dists = (const float*)d_in[3];
    const float* W1    = (const float*)d_in[4];
    const float* b1    = (const float*)d_in[5];
    const float* W2    = (const float*)d_in[6];
    const float* b2    = (const float*)d_in[7];
    const float* W3    = (const float*)d_in[8];
    const float* b3    = (const float*)d_in[9];
    float* out = (float*)d_out;

    u16* ws = (u16*)d_ws;   // 61440 (W1r) + 16384 (W2r) + 2048 (W3r) u16 = 159744 B

    prep_kernel<<<312, 256, 0, stream>>>(W1, W2, W3, ws);
    render_kernel<<<NBLOCKS, 512, 0, stream>>>(sigma, app, view, dists,
                                               b1, b2, b3, ws, out);
}

// Round 3
// 206.731 us; speedup vs baseline: 1.2308x; 1.0467x over previous
//
#include <hip/hip_runtime.h>
#include <math.h>

typedef unsigned short u16;
using bf16x8 = __attribute__((ext_vector_type(8))) short;
using f32x4  = __attribute__((ext_vector_type(4))) float;

#define NS      128
#define NBLOCKS 4096    // 1 ray per block, 512 threads (8 waves)
#define KS1     15      // 30 channels * 16 slots = 480 K (W1 slices)
#define NSLICE  19      // 15 (W1) + 4 (W2) unified W slices of 4096 u16

// LDS pool (u16 units): X quad-buffer = 2 groups x 2 slices x 4096 u16
// (32 KB), fully overlaid by h [128x128] bf16 after GEMM1. W is never
// staged: B-frags stream from L2-resident ws straight into registers.
#define POOLSZ 16384

// Raw barrier: drain LDS only (producer->consumer visibility), leave global
// loads (register prefetches) in flight across the barrier. __syncthreads()
// would drain vmcnt(0) and put an L2 round-trip on every phase.
#define BAR() do { asm volatile("s_waitcnt lgkmcnt(0)" ::: "memory");        \
                   __builtin_amdgcn_s_barrier();                              \
                   asm volatile("" ::: "memory"); } while (0)

#define MF(A,B,C) __builtin_amdgcn_mfma_f32_16x16x32_bf16((A),(B),(C),0,0,0)

__device__ __forceinline__ u16 f2bf(float f) {           // host-prep path only
    unsigned int i = __float_as_uint(f);
    return (u16)((i + 0x7FFFu + ((i >> 16) & 1u)) >> 16);  // RNE
}

// pack two floats to bf16 pair [hi:lo] in one dword (single VALU op, RNE)
__device__ __forceinline__ unsigned pk(float hi, float lo) {
    unsigned r;
    asm("v_cvt_pk_bf16_f32 %0, %1, %2" : "=v"(r) : "v"(lo), "v"(hi));
    return r;
}
__device__ __forceinline__ u16 f2bf1(float f) {
    return (u16)((__float_as_uint(f) + 0x8000u) >> 16);
}

// Swizzled A-frag-order offset for the h [128x128] region: XOR (k>>3)&3 into
// the chunk index (readers apply chunk^quad) to spread the epilogue's
// column-wise u16 writes across more banks.
__device__ __forceinline__ int afoff_h(int m, int k) {
    int chunk = ((k >> 5) * 8 + (m >> 4)) * 64 + ((k >> 3) & 3) * 16 + (m & 15);
    chunk ^= (k >> 3) & 3;
    return chunk * 8 + (k & 7);
}

// channel/slot -> original mlp_in k index (reference ordering)
__device__ __forceinline__ int orig_k(int ch, int slot) {
    if (ch < 27) {
        if (slot == 0) return ch;
        if (slot <= 6) return 30 + ch * 6 + (slot - 1);     // sin(app)
        return 192 + ch * 6 + (slot - 7);                    // cos(app)
    } else {
        int c = ch - 27;
        if (slot == 0) return 27 + c;
        if (slot <= 6) return 354 + c * 6 + (slot - 1);      // sin(view)
        return 372 + c * 6 + (slot - 7);                     // cos(view)
    }
}

__device__ __forceinline__ float ldch(const float* ap, const float* vp, int c) {
    return (c < 27) ? ap[c] : vp[c - 27];
}

// build one channel-half of a frag-order X slice: thread (m_b, cl_b) owns
// chunks 2cl_b, 2cl_b+1 of group g=m_b>>4; slots [v, sin f0..5, cos f0..5, 0x3]
__device__ __forceinline__ void build_x(u16* Xb, int m_b, int cl_b, float v) {
    float rev = v * 0.15915494309189535f;
    rev -= floorf(rev);
    float s0 = __builtin_amdgcn_sinf(rev);
    float c0 = __builtin_amdgcn_cosf(rev);
    float s1 = 2.f * s0 * c0, c1 = c0 * c0 - s0 * s0;
    float s2 = 2.f * s1 * c1, c2 = c1 * c1 - s1 * s1;
    float s3 = 2.f * s2 * c2, c3 = c2 * c2 - s2 * s2;
    float s4 = 2.f * s3 * c3, c4 = c3 * c3 - s3 * s3;
    float s5 = 2.f * s4 * c4, c5 = c4 * c4 - s4 * s4;
    uint4 lo, hi;
    lo.x = pk(s0, v);  lo.y = pk(s2, s1);  lo.z = pk(s4, s3);  lo.w = pk(c0, s5);
    hi.x = pk(c2, c1); hi.y = pk(c4, c3);  hi.z = pk(0.f, c5); hi.w = 0u;
    int base = (m_b >> 4) * 512 + ((2 * cl_b) * 16 + (m_b & 15)) * 8;
    *(uint4*)(Xb + base)       = lo;   // chunk 2*cl_b
    *(uint4*)(Xb + base + 128) = hi;   // chunk 2*cl_b+1 (+16*8 u16)
}

// W1 -> 15 slices, W2 -> 4 slices, W3 -> 4 mini B-frag slices (N padded 16)
__global__ __launch_bounds__(256) void prep_kernel(
    const float* __restrict__ W1, const float* __restrict__ W2,
    const float* __restrict__ W3, u16* __restrict__ ws)
{
    int idx = blockIdx.x * 256 + threadIdx.x;
    if (idx < 61440) {                               // W1r: [ks15][nt8][lane64][j8]
        int j = idx & 7, lane = (idx >> 3) & 63, nt = (idx >> 9) & 7, ks = idx >> 12;
        int q = lane >> 4, l15 = lane & 15;
        int klocal = q * 8 + j;                      // 0..31
        int ch = ks * 2 + (klocal >> 4);
        int slot = klocal & 15;
        int n = nt * 16 + l15;
        ws[idx] = (slot < 13) ? f2bf(W1[orig_k(ch, slot) * 128 + n]) : (u16)0;
    } else if (idx < 77824) {                        // W2r: [ks4][nt8][lane64][j8]
        int i2 = idx - 61440;
        int j = i2 & 7, lane = (i2 >> 3) & 63, nt = (i2 >> 9) & 7, ks = i2 >> 12;
        int k = ks * 32 + (lane >> 4) * 8 + j;
        int n = nt * 16 + (lane & 15);
        ws[idx] = f2bf(W2[k * 128 + n]);
    } else if (idx < 79872) {                        // W3r: [ks4][lane64][j8], N pad 16
        int i3 = idx - 77824;
        int j = i3 & 7, lane = (i3 >> 3) & 63, ks = i3 >> 9;
        int k = ks * 32 + (lane >> 4) * 8 + j;
        int n = lane & 15;
        ws[idx] = (n < 3) ? f2bf(W3[k * 3 + n]) : (u16)0;
    }
}

// One 2-slice phase (group g = unified slices 2g, 2g+1). Named B registers
// (ping-pong via macro args) so nothing is demoted to scratch.
#define PHASE(g, BC0,BC1,BC2,BC3, BN0,BN1,BN2,BN3)                            \
  {                                                                           \
    const u16* wpn = wp0 + (2*(g)+2) * 4096;       /* prefetch group g+1 */   \
    BN0 = *(const bf16x8*)(wpn);                                              \
    BN1 = *(const bf16x8*)(wpn + 512);                                        \
    BN2 = *(const bf16x8*)(wpn + 4096);                                       \
    BN3 = *(const bf16x8*)(wpn + 4096 + 512);                                 \
    if (4*((g)+2) + cl < 30)                       /* input for group g+2 */  \
        pv_nxt = ldch(ap, vp, 4*((g)+2) + cl);                                \
    const u16* ab = pool + ((((g)&1) ? 8192 : 0)) + (wm*256 + lane)*8;        \
    bf16x8 a0 = *(const bf16x8*)(ab);                                         \
    bf16x8 a1 = *(const bf16x8*)(ab + 512);                                   \
    bf16x8 a2 = *(const bf16x8*)(ab + 1024);                                  \
    bf16x8 a3 = *(const bf16x8*)(ab + 1536);                                  \
    acc[0][0]=MF(a0,BC0,acc[0][0]); acc[0][1]=MF(a0,BC1,acc[0][1]);           \
    acc[1][0]=MF(a1,BC0,acc[1][0]); acc[1][1]=MF(a1,BC1,acc[1][1]);           \
    acc[2][0]=MF(a2,BC0,acc[2][0]); acc[2][1]=MF(a2,BC1,acc[2][1]);           \
    acc[3][0]=MF(a3,BC0,acc[3][0]); acc[3][1]=MF(a3,BC1,acc[3][1]);           \
    a0 = *(const bf16x8*)(ab + 4096);                                         \
    a1 = *(const bf16x8*)(ab + 4096 + 512);                                   \
    a2 = *(const bf16x8*)(ab + 4096 + 1024);                                  \
    a3 = *(const bf16x8*)(ab + 4096 + 1536);                                  \
    acc[0][0]=MF(a0,BC2,acc[0][0]); acc[0][1]=MF(a0,BC3,acc[0][1]);           \
    acc[1][0]=MF(a1,BC2,acc[1][0]); acc[1][1]=MF(a1,BC3,acc[1][1]);           \
    acc[2][0]=MF(a2,BC2,acc[2][0]); acc[2][1]=MF(a2,BC3,acc[2][1]);           \
    acc[3][0]=MF(a3,BC2,acc[3][0]); acc[3][1]=MF(a3,BC3,acc[3][1]);           \
    if (4*((g)+1) + cl < 30)                       /* build group g+1 */      \
        build_x(pool + ((((g)+1)&1) ? 8192 : 0) + (cl>>1)*4096, row, cl&1,    \
                pv_cur);                                                      \
    pv_cur = pv_nxt;                                                          \
    BAR();                                                                    \
  }

// 8 waves: wave (wm = wave>>2, wn = wave&3) owns a 64x32 output tile.
// 13 lgkm-only barriers per ray; global prefetches stay in flight across them.
__global__ __launch_bounds__(512, 4) void render_kernel(
    const float* __restrict__ sigma_g, const float* __restrict__ app_g,
    const float* __restrict__ view_g,  const float* __restrict__ dists_g,
    const float* __restrict__ b1_g,    const float* __restrict__ b2_g,
    const float* __restrict__ b3_g,    const u16* __restrict__ ws,
    float* __restrict__ out_g)
{
    __shared__ __align__(16) u16 pool[POOLSZ];
    __shared__ __align__(16) float part[NS * 3];
    __shared__ float scanS;          // wave0 scan total broadcast
    __shared__ float sum2[6];        // per-wave final partials

    const int tid  = threadIdx.x;
    const int lane = tid & 63;
    const int wave = tid >> 6;       // 0..7
    const int l15  = lane & 15;
    const int quad = lane >> 4;
    const int wm   = wave >> 2;      // row half (64 rows)
    const int wn   = wave & 3;       // col quarter (32 cols)

    const int r  = blockIdx.x;
    const int rb = r * NS;
    const int row = tid & 127;       // X-build row (all 512 threads build)
    const int cl  = tid >> 7;        // X-build channel-local 0..3 (2 slices)
    const float* ap = app_g  + (rb + row) * 27;
    const float* vp = view_g + (rb + row) * 3;

    // issue B loads for group 0 (slices 0,1) ASAP
    const u16* wp0 = ws + (wn * 128 + lane) * 8;
    bf16x8 bP0, bP1, bP2, bP3, bQ0, bQ1, bQ2, bQ3;
    bP0 = *(const bf16x8*)(wp0);
    bP1 = *(const bf16x8*)(wp0 + 512);
    bP2 = *(const bf16x8*)(wp0 + 4096);
    bP3 = *(const bf16x8*)(wp0 + 4096 + 512);

    // b1 needed at the h1 epilogue: 2 regs
    const float b1r0 = b1_g[wn * 32 + l15];
    const float b1r1 = b1_g[wn * 32 + 16 + l15];

    // rolling input prefetch (2 resident)
    float pv_cur = ldch(ap, vp, cl);             // group 0: ch = cl
    float pv_nxt = ldch(ap, vp, 4 + cl);         // group 1: ch = 4+cl

    // ---- alpha + shuffle transmittance scan (waves 0,1) ----
    float alpha = 0.f, prod = 1.f, wr = 0.f;
    if (tid < NS) {
        float x  = sigma_g[rb + tid] - 10.f;
        float sp = (x > 20.f) ? x : log1pf(expf(x));
        alpha = 1.f - expf(-sp * dists_g[rb + tid] * 25.f);
        if (tid == NS - 1) alpha = 1.f;
        float tb = 1.f - alpha + 1e-10f;
        prod = tb;
        #pragma unroll
        for (int d = 1; d < 64; d <<= 1) {
            float v = __shfl_up(prod, d);
            if (lane >= d) prod *= v;
        }
        if (tid == 63) scanS = prod;
    }

    // ---- build X group 0 (slices 0,1; channels 0..3) into buf0 ----
    build_x(pool + (cl >> 1) * 4096, row, cl & 1, pv_cur);
    pv_cur = pv_nxt;
    BAR();

    // finish weights: wr = alpha * T_exclusive
    if (tid < NS) {
        float prev = __shfl_up(prod, 1);
        float base = (lane == 0) ? 1.f : prev;
        float scale = (wave == 1) ? scanS : 1.f;
        wr = alpha * base * scale;
    }

    const f32x4 vzero = {0.f, 0.f, 0.f, 0.f};
    f32x4 acc[4][2];
    #pragma unroll
    for (int mt = 0; mt < 4; ++mt)
        #pragma unroll
        for (int nt = 0; nt < 2; ++nt) acc[mt][nt] = vzero;

    // ---- GEMM1 phases: groups 0..6 (slices 0..13) ----
    #pragma unroll 1
    for (int t = 0; t < 3; ++t) {
        PHASE(2 * t,     bP0, bP1, bP2, bP3, bQ0, bQ1, bQ2, bQ3);
        PHASE(2 * t + 1, bQ0, bQ1, bQ2, bQ3, bP0, bP1, bP2, bP3);
    }
    PHASE(6, bP0, bP1, bP2, bP3, bQ0, bQ1, bQ2, bQ3);
    // after phase 6: bQ = slices 14,15 (group-7 prefetch crossed into W2)

    // ---- phase 7: slice 14 + W2 tail prefetch (slices 16..18) ----
    {
        const u16* wpn = wp0 + 16 * 4096;
        bf16x8 w2a0 = *(const bf16x8*)(wpn);
        bf16x8 w2a1 = *(const bf16x8*)(wpn + 512);
        bf16x8 w2b0 = *(const bf16x8*)(wpn + 4096);
        bf16x8 w2b1 = *(const bf16x8*)(wpn + 4096 + 512);
        bf16x8 w2c0 = *(const bf16x8*)(wpn + 8192);
        bf16x8 w2c1 = *(const bf16x8*)(wpn + 8192 + 512);

        const u16* ab = pool + 8192 + (wm * 256 + lane) * 8;  // buf1: slice 14
        bf16x8 a0 = *(const bf16x8*)(ab);
        bf16x8 a1 = *(const bf16x8*)(ab + 512);
        bf16x8 a2 = *(const bf16x8*)(ab + 1024);
        bf16x8 a3 = *(const bf16x8*)(ab + 1536);
        acc[0][0]=MF(a0,bQ0,acc[0][0]); acc[0][1]=MF(a0,bQ1,acc[0][1]);
        acc[1][0]=MF(a1,bQ0,acc[1][0]); acc[1][1]=MF(a1,bQ1,acc[1][1]);
        acc[2][0]=MF(a2,bQ0,acc[2][0]); acc[2][1]=MF(a2,bQ1,acc[2][1]);
        acc[3][0]=MF(a3,bQ0,acc[3][0]); acc[3][1]=MF(a3,bQ1,acc[3][1]);
        BAR();   // all slice-14 A-reads done before h1 overwrites X

        // epilogue 1: h1 = relu(acc + b1) -> pool (bf16, swizzled frag order)
        #pragma unroll
        for (int mt = 0; mt < 4; ++mt)
            #pragma unroll
            for (int nt = 0; nt < 2; ++nt) {
                int col = wn * 32 + nt * 16 + l15;
                #pragma unroll
                for (int rr = 0; rr < 4; ++rr) {
                    int rw = wm * 64 + mt * 16 + quad * 4 + rr;
                    pool[afoff_h(rw, col)] =
                        f2bf1(fmaxf(acc[mt][nt][rr] + ((nt == 0) ? b1r0 : b1r1), 0.f));
                }
                acc[mt][nt] = vzero;          // reset for GEMM2
            }
        BAR();   // h1 visible to all waves

        // ---- GEMM2: slices 15..18 (h1 @ W2), one barrier-free phase ----
        #define G2(ks, B0, B1)                                                \
          {                                                                   \
            int cb = ((ks) * 512 + wm * 256 + lane) ^ quad;                   \
            bf16x8 h0 = *(const bf16x8*)(pool + cb * 8);                      \
            bf16x8 h1v = *(const bf16x8*)(pool + (cb + 64) * 8);              \
            bf16x8 h2v = *(const bf16x8*)(pool + (cb + 128) * 8);             \
            bf16x8 h3v = *(const bf16x8*)(pool + (cb + 192) * 8);             \
            acc[0][0]=MF(h0,B0,acc[0][0]); acc[0][1]=MF(h0,B1,acc[0][1]);     \
            acc[1][0]=MF(h1v,B0,acc[1][0]); acc[1][1]=MF(h1v,B1,acc[1][1]);   \
            acc[2][0]=MF(h2v,B0,acc[2][0]); acc[2][1]=MF(h2v,B1,acc[2][1]);   \
            acc[3][0]=MF(h3v,B0,acc[3][0]); acc[3][1]=MF(h3v,B1,acc[3][1]);   \
          }
        G2(0, bQ2, bQ3);
        G2(1, w2a0, w2a1);
        G2(2, w2b0, w2b1);
        G2(3, w2c0, w2c1);
        #undef G2
        BAR();   // all GEMM2 h1-reads done before h2 overwrites
    }

    // ---- epilogue 2: h2 = relu(acc + b2) -> overlays h1 ----
    const float b2r0 = b2_g[wn * 32 + l15];
    const float b2r1 = b2_g[wn * 32 + 16 + l15];
    #pragma unroll
    for (int mt = 0; mt < 4; ++mt)
        #pragma unroll
        for (int nt = 0; nt < 2; ++nt) {
            int col = wn * 32 + nt * 16 + l15;
            #pragma unroll
            for (int rr = 0; rr < 4; ++rr) {
                int rw = wm * 64 + mt * 16 + quad * 4 + rr;
                pool[afoff_h(rw, col)] =
                    f2bf1(fmaxf(acc[mt][nt][rr] + ((nt == 0) ? b2r0 : b2r1), 0.f));
            }
        }
    BAR();

    // ---- layer 3 via MFMA: rgb = sigmoid(h2 @ W3 + b3); wave = row-tile ----
    const u16* w3r = ws + 77824;
    const float b3v = (l15 < 3) ? b3_g[l15] : 0.f;
    f32x4 acc3 = vzero;
    #pragma unroll
    for (int ks = 0; ks < 4; ++ks) {
        bf16x8 w3f = *(const bf16x8*)(w3r + (ks * 64 + lane) * 8);
        int c = ((ks * 8 + wave) * 64 + lane) ^ quad;
        bf16x8 a3 = *(const bf16x8*)(pool + c * 8);
        acc3 = MF(a3, w3f, acc3);
    }
    if (l15 < 3) {
        #pragma unroll
        for (int rr = 0; rr < 4; ++rr) {
            int rw = wave * 16 + quad * 4 + rr;
            float v = acc3[rr] + b3v;
            part[rw * 3 + l15] = 1.f / (1.f + expf(-v));
        }
    }
    BAR();

    // ---- weighted sum over samples ----
    if (tid < NS) {
        float v0 = wr * part[tid * 3 + 0];
        float v1 = wr * part[tid * 3 + 1];
        float v2 = wr * part[tid * 3 + 2];
        #pragma unroll
        for (int d = 1; d < 64; d <<= 1) {
            v0 += __shfl_xor(v0, d);
            v1 += __shfl_xor(v1, d);
            v2 += __shfl_xor(v2, d);
        }
        if (lane == 0) {
            sum2[wave * 3 + 0] = v0;
            sum2[wave * 3 + 1] = v1;
            sum2[wave * 3 + 2] = v2;
        }
    }
    BAR();
    if (tid == 0) {
        out_g[r * 3 + 0] = sum2[0] + sum2[3];
        out_g[r * 3 + 1] = sum2[1] + sum2[4];
        out_g[r * 3 + 2] = sum2[2] + sum2[5];
    }
}

extern "C" void kernel_launch(void* const* d_in, const int* in_sizes, int n_in,
                              void* d_out, int out_size, void* d_ws, size_t ws_size,
                              hipStream_t stream) {
    (void)in_sizes; (void)n_in; (void)out_size; (void)ws_size;
    const float* sigma = (const float*)d_in[0];
    const float* app   = (const float*)d_in[1];
    const float* view  = (const float*)d_in[2];
    const float* dists = (const float*)d_in[3];
    const float* W1    = (const float*)d_in[4];
    const float* b1    = (const float*)d_in[5];
    const float* W2    = (const float*)d_in[6];
    const float* b2    = (const float*)d_in[7];
    const float* W3    = (const float*)d_in[8];
    const float* b3    = (const float*)d_in[9];
    float* out = (float*)d_out;

    u16* ws = (u16*)d_ws;   // 61440 (W1r) + 16384 (W2r) + 2048 (W3r) u16 = 159744 B

    prep_kernel<<<312, 256, 0, stream>>>(W1, W2, W3, ws);
    render_kernel<<<NBLOCKS, 512, 0, stream>>>(sigma, app, view, dists,
                                               b1, b2, b3, ws, out);
}